// Round 6
// baseline (142.544 us; speedup 1.0000x reference)
//
#include <hip/hip_runtime.h>

// PointGatedBlock: SE3 point conv + gated nonlinearity. fp32 in/out.
// R6: true pipeline (prefetch issued AFTER the barrier so __syncthreads'
// vmcnt(0) never drains in-flight prefetches) + XOR-swizzled LDS (stride 64,
// block^=row&7) killing the 4-way bank conflicts on GEMM1 column reads.
// Pre-kernel converts W+feat to bf16 in d_ws once.
// Main: grid 512 = (b, 8-n); block 512 (8 waves); LDS 66.6KB -> 2 blocks/CU.
//  phi[(n,k)=128 rows][64 m] bf16 (log-space recurrence, 2 exp2 per k-pair)
//  feat[112 rows][64 m] bf16 (rows 104..111 zero)
//  GEMM1: waves = 4 rowgroups x 2 colgroups; 2 rowtiles x 4|3 coltiles each.
//  GEMM2: y[144 o][8 n]; A-frags = bf16 W from ws. epilogue: relu/sigmoid-gate.

typedef __attribute__((ext_vector_type(4))) float f32x4;
typedef __attribute__((ext_vector_type(8))) short s16x8;

#define DI 104
#define DO 144
#define MT 64
#define TTST 1688          // Tt row stride (elems): 844 dwords -> 12-bank row skew
#define YST 9

#define W_ELEMS 239616     // 16*144*104
#define F_ELEMS 425984     // 4*104*1024

// LDS byte offsets (phi/feat rows: 64 elems = 128 B, XOR-swizzled blocks)
#define OFF_PHI0 0
#define OFF_PHI1 16384                  // 128*64*2
#define OFF_FEAT0 32768
#define OFF_FEAT1 47104                 // + 112*64*2 = 14336
#define OFF_Y 61440
#define SMEM_TOTAL (61440 + 144*9*4)    // 66624 B -> 2 blocks/CU

__device__ __forceinline__ float fexp2(float x) {
#if __has_builtin(__builtin_amdgcn_exp2f)
    return __builtin_amdgcn_exp2f(x);
#else
    return exp2f(x);
#endif
}
__device__ __forceinline__ float flog2(float x) {
#if __has_builtin(__builtin_amdgcn_logf)
    return __builtin_amdgcn_logf(x);
#else
    return log2f(x);
#endif
}
__device__ __forceinline__ float fsqrt_(float x) {
#if __has_builtin(__builtin_amdgcn_sqrtf)
    return __builtin_amdgcn_sqrtf(x);
#else
    return sqrtf(x);
#endif
}
__device__ __forceinline__ float frcp_(float x) {
#if __has_builtin(__builtin_amdgcn_rcpf)
    return __builtin_amdgcn_rcpf(x);
#else
    return 1.0f / x;
#endif
}
__device__ __forceinline__ unsigned int pkbf(float lo, float hi) {
    unsigned int a = __builtin_bit_cast(unsigned int, lo) + 0x8000u;
    unsigned int b = __builtin_bit_cast(unsigned int, hi) + 0x8000u;
    return __builtin_amdgcn_perm(b, a, 0x07060302u);
}
__device__ __forceinline__ unsigned short f2b(float f) {
    return (unsigned short)((__builtin_bit_cast(unsigned int, f) + 0x8000u) >> 16);
}

// ---- pre-kernel: fp32 -> bf16 for W (ws[0..W_ELEMS)) and feat (ws[W_ELEMS..)) ----
__global__ __launch_bounds__(256, 8)
void cvt_kernel(const float* __restrict__ feat_g, const float* __restrict__ W_g,
                unsigned short* __restrict__ ws)
{
    int gid = blockIdx.x * 256 + threadIdx.x;           // 8 elems per thread
    const float* src;
    unsigned short* dst;
    if (gid < W_ELEMS/8) {
        src = W_g + gid*8;  dst = ws + gid*8;
    } else {
        int g2 = gid - W_ELEMS/8;
        src = feat_g + g2*8; dst = ws + W_ELEMS + g2*8;
    }
    f32x4 a = *(const f32x4*)src;
    f32x4 b = *(const f32x4*)(src + 4);
    unsigned int o[4] = { pkbf(a[0],a[1]), pkbf(a[2],a[3]), pkbf(b[0],b[1]), pkbf(b[2],b[3]) };
    *(f32x4*)dst = *(f32x4*)o;
}

__global__ __launch_bounds__(512, 4)
void pgb_kernel(const unsigned short* __restrict__ ws,   // Wbf | featbf
                const float* __restrict__ diff_g,
                const float* __restrict__ mask_g,
                float* __restrict__ out_g)
{
    const unsigned short* Wbf    = ws;
    const unsigned short* featbf = ws + W_ELEMS;

    __shared__ __align__(16) unsigned char smem[SMEM_TOTAL];
    unsigned short* Tt   = (unsigned short*)(smem);      // aliases phi bufs (post-barrier)
    float*          ylds = (float*)(smem + OFF_Y);

    const int t    = threadIdx.x;
    const int b    = blockIdx.x >> 7;
    const int n0   = (blockIdx.x & 127) << 3;
    const int wave = t >> 6;
    const int lane = t & 63;
    const int l15  = lane & 15;
    const int q    = lane >> 4;
    const int wr   = wave >> 1;          // rowgroup: rowtiles 2wr, 2wr+1 (n_local)
    const int ct0  = (wave & 1) << 2;    // colgroup: coltiles ct0..ct0+3 (skip 7)
    const int sw   = l15 & 7;            // read-side swizzle key (row&7)

    // zero feat pad rows 104..111 in both buffers (8 rows x 64 elems = 256 dwords)
    if (t < 256) {
        ((unsigned int*)(smem + OFF_FEAT0 + DI*128))[t] = 0u;
        ((unsigned int*)(smem + OFF_FEAT1 + DI*128))[t] = 0u;
    }

    f32x4 acc[2][4];
#pragma unroll
    for (int rr = 0; rr < 2; ++rr)
#pragma unroll
        for (int cc = 0; cc < 4; ++cc)
            acc[rr][cc] = (f32x4){0.f, 0.f, 0.f, 0.f};

    // phi thread mapping: 8 n x 2 k-halves x 32 m-pairs
    const int pn = t >> 6;               // n-row 0..7 (== wave)
    const int kh = (t >> 5) & 1;         // k-half: k0 = 8*kh
    const int pml = (t & 31) << 1;       // m pair (even), 0..62
    const int pblk = (t & 31) >> 2;      // m block 0..7 (write-side swizzle base)
    const int pin  = pml & 7;            // within-block offset
    const float CEXP = -23.083120654223414f;   // -GAMMA * log2(e)
    const float A1   = 6.155498841126244f;     // -2*CEXP*DL
    const float V2   = -0.8207331788168325f;   // 2*CEXP*DL^2
    const float K0OFF = kh ? 1.0666666666666667f : 0.f;       // k0*DL
    const float S0B   = kh ? -6.976232019943076f : -0.41036658940841624f; // A0+V2*k0
    const size_t dmrow = (size_t)((b << 10) + n0 + pn) << 10;

    // feat staging mapping: 832 16B-chunks; thread t -> chunk t (+ chunk 512+t if t<320)
    const int fi0 = t >> 3, fj = t & 7;
    const int fi1 = 64 + (t >> 3);
    const int fjs = (fj ^ (fi0 & 7)) << 3;   // swizzled block offset (fi1&7 == fi0&7)
    const size_t fbase = (size_t)b * DI << 10;

    // ---- prologue: tile 0 registers ----
    float dx0, dy0, dz0, dx1, dy1, dz1, mk0, mk1;
    s16x8 fr0 = {}, fr1 = {};
    {
        const float* dp = diff_g + (dmrow + pml)*3;
        dx0=dp[0]; dy0=dp[1]; dz0=dp[2]; dx1=dp[3]; dy1=dp[4]; dz1=dp[5];
        const float* mp = mask_g + dmrow + pml;
        mk0=mp[0]; mk1=mp[1];
        fr0 = *(const s16x8*)(featbf + fbase + ((size_t)fi0 << 10) + (fj << 3));
        if (t < 320)
            fr1 = *(const s16x8*)(featbf + fbase + ((size_t)fi1 << 10) + (fj << 3));
    }

    for (int s = 0; s < 16; ++s) {
        const int ms = s * MT;
        unsigned short* phibuf  = (unsigned short*)(smem + ((s & 1) ? OFF_PHI1 : OFF_PHI0));
        unsigned short* featbuf = (unsigned short*)(smem + ((s & 1) ? OFF_FEAT1 : OFF_FEAT0));
        // (a) phi(s): log-space recurrence, 8 k x 2 m per thread (regs from iter s-1)
        {
            float r0 = fsqrt_(fmaf(dx0,dx0, fmaf(dy0,dy0, fmaf(dz0,dz0, 1e-12f))));
            float r1 = fsqrt_(fmaf(dx1,dx1, fmaf(dy1,dy1, fmaf(dz1,dz1, 1e-12f))));
            float t0 = r0 - K0OFF, t1 = r1 - K0OFF;
            float E0 = fmaf(CEXP*t0, t0, flog2(mk0));
            float E1 = fmaf(CEXP*t1, t1, flog2(mk1));
            float s0 = fmaf(A1, r0, S0B);
            float s1 = fmaf(A1, r1, S0B);
            unsigned short* pw = phibuf + (pn*16 + kh*8)*64 + pin;
#pragma unroll
            for (int j = 0; j < 8; ++j) {
                float p0 = fexp2(E0);
                float p1 = fexp2(E1);
                *(unsigned int*)(pw + j*64 + ((pblk ^ j) << 3)) = pkbf(p0, p1);
                E0 += s0; s0 += V2;
                E1 += s1; s1 += V2;
            }
        }
        // (b) feat(s) -> LDS (bf16 passthrough, swizzled b128 writes)
        *(s16x8*)(featbuf + fi0*64 + fjs) = fr0;
        if (t < 320)
            *(s16x8*)(featbuf + fi1*64 + fjs) = fr1;
        // (c) barrier — all vmem already consumed; drain costs nothing
        __syncthreads();
        // (d) NOW issue tile s+1 prefetch: covered by GEMM1(s), consumed at (a)
        //     of iter s+1, long before the next barrier.
        if (s < 15) {
            const float* dp = diff_g + (dmrow + ms + MT + pml)*3;
            dx0=dp[0]; dy0=dp[1]; dz0=dp[2]; dx1=dp[3]; dy1=dp[4]; dz1=dp[5];
            const float* mp = mask_g + dmrow + ms + MT + pml;
            mk0=mp[0]; mk1=mp[1];
            fr0 = *(const s16x8*)(featbf + fbase + ((size_t)fi0 << 10) + ms + MT + (fj << 3));
            if (t < 320)
                fr1 = *(const s16x8*)(featbf + fbase + ((size_t)fi1 << 10) + ms + MT + (fj << 3));
        }
        // (e) GEMM1 on tile s (swizzled reads: block = (kk*4+q) ^ (row&7))
#pragma unroll
        for (int kk = 0; kk < 2; ++kk) {
            const int mo = ((kk*4 + q) ^ sw) << 3;
            s16x8 a0 = *(const s16x8*)(phibuf + ((2*wr    )*16 + l15)*64 + mo);
            s16x8 a1 = *(const s16x8*)(phibuf + ((2*wr + 1)*16 + l15)*64 + mo);
#pragma unroll
            for (int cc = 0; cc < 4; ++cc) {
                if (ct0 + cc < 7) {
                    s16x8 bf = *(const s16x8*)(featbuf + ((ct0+cc)*16 + l15)*64 + mo);
                    acc[0][cc] = __builtin_amdgcn_mfma_f32_16x16x32_bf16(a0, bf, acc[0][cc], 0, 0, 0);
                    acc[1][cc] = __builtin_amdgcn_mfma_f32_16x16x32_bf16(a1, bf, acc[1][cc], 0, 0, 0);
                }
            }
        }
    }

    __syncthreads();   // phi bufs free -> Tt may overwrite

    // ---- acc (C: col=l15=i_local, row=q*4+r=k; tiles (n_local, i-tile)) -> Tt[n][k*104+i]
#pragma unroll
    for (int rr = 0; rr < 2; ++rr) {
        int nloc = 2*wr + rr;
#pragma unroll
        for (int cc = 0; cc < 4; ++cc) {
            int i = (ct0+cc)*16 + l15;
            if (ct0 + cc < 7 && i < DI) {
#pragma unroll
                for (int r = 0; r < 4; ++r)
                    Tt[nloc*TTST + (q*4+r)*DI + i] = f2b(acc[rr][cc][r]);
            }
        }
    }
    __syncthreads();

    // ---- GEMM2: y[o,n] = sum_ki Wbf[k,o,i]*Tt[n][ki]; 52 K-steps of 32 ----
    f32x4 y0 = (f32x4){0.f,0.f,0.f,0.f}, y1 = (f32x4){0.f,0.f,0.f,0.f};
    const int o0 = wave*16 + l15;
    const int o1 = 128 + l15;            // o-tile 8, wave 0's second acc
#pragma unroll 4
    for (int s3 = 0; s3 < 52; ++s3) {
        int a = s3*4 + q;                // 8-elem ki block; k=a/13, i=(a%13)*8
        int k = a / 13;
        int i = (a - k*13) << 3;
        s16x8 bf = *(const s16x8*)(Tt + (l15 & 7)*TTST + s3*32 + q*8);
        s16x8 af = *(const s16x8*)(Wbf + (size_t)(k*DO + o0)*DI + i);
        y0 = __builtin_amdgcn_mfma_f32_16x16x32_bf16(af, bf, y0, 0, 0, 0);
        if (wave == 0) {
            s16x8 ag = *(const s16x8*)(Wbf + (size_t)(k*DO + o1)*DI + i);
            y1 = __builtin_amdgcn_mfma_f32_16x16x32_bf16(ag, bf, y1, 0, 0, 0);
        }
    }
    if (l15 < 8) {
#pragma unroll
        for (int r = 0; r < 4; ++r)
            ylds[(wave*16 + q*4 + r)*YST + l15] = y0[r];
        if (wave == 0) {
#pragma unroll
            for (int r = 0; r < 4; ++r)
                ylds[(128 + q*4 + r)*YST + l15] = y1[r];
        }
    }
    __syncthreads();

    // ---- gating epilogue: out[b, o(<120), n0+nn] fp32 ----
    const float L2E = 1.4426950408889634f;
    for (int idx = t; idx < 120*8; idx += 512) {
        int o = idx >> 3, nn = idx & 7;
        float y = ylds[o*YST + nn];
        float v;
        if (o < 32) {
            v = fmaxf(y, 0.f);
        } else if (o < 80) {
            float g = ylds[(120 + (o-32)/3)*YST + nn];
            v = y * frcp_(1.f + fexp2(-g*L2E));
        } else {
            float g = ylds[(136 + (o-80)/5)*YST + nn];
            v = y * frcp_(1.f + fexp2(-g*L2E));
        }
        out_g[((size_t)(b*120 + o) << 10) + n0 + nn] = v;
    }
}

extern "C" void kernel_launch(void* const* d_in, const int* in_sizes, int n_in,
                              void* d_out, int out_size, void* d_ws, size_t ws_size,
                              hipStream_t stream) {
    const float* feat = (const float*)d_in[0];  // [4,104,1024] fp32
    const float* diff = (const float*)d_in[1];  // [4,1024,1024,3] fp32
    const float* mask = (const float*)d_in[2];  // [4,1024,1024] fp32
    const float* W    = (const float*)d_in[3];  // [16,144,104] fp32
    float* out = (float*)d_out;                 // [4,120,1024] fp32
    unsigned short* ws = (unsigned short*)d_ws; // Wbf (479 KB) + featbf (852 KB)
    (void)in_sizes; (void)n_in; (void)out_size; (void)ws_size;
    cvt_kernel<<<dim3((W_ELEMS + F_ELEMS)/8/256), dim3(256), 0, stream>>>(feat, W, ws);
    pgb_kernel<<<dim3(512), dim3(512), 0, stream>>>(ws, diff, mask, out);
}